// Round 7
// baseline (115.337 us; speedup 1.0000x reference)
//
#include <hip/hip_runtime.h>

#define NB 1024
#define ND 256
#define MARGINF 0.3f
#define BIGV 1e9f
#define D2R 0.017453292519943295f
#define HD2R 0.008726646259971648f

// haversine 'a' thresholds: sin^2(T/(2*6371000)) (validated rounds 1-6)
#define A_POS 3.8495040e-12f   // 25 m
#define A_NEG 6.1592064e-11f   // 100 m

__device__ __forceinline__ float d4(float4 a, float4 b, float acc) {
    return fmaf(a.x,b.x, fmaf(a.y,b.y, fmaf(a.z,b.z, fmaf(a.w,b.w, acc))));
}

// =================== NEW PATH ===================

// K1: per-point prep {sqnorm, lat_deg, lon_deg, cos(lat)}
__global__ __launch_bounds__(256) void prep_kernel(
    const float* __restrict__ emb, const float* __restrict__ gps,
    float4* __restrict__ prep)
{
    const int tid = threadIdx.x;
    const int row = blockIdx.x*16 + (tid >> 4);
    const int kk  = tid & 15;
    const float4* r4 = (const float4*)emb + (size_t)row*64;
    float s = 0.f;
    #pragma unroll
    for (int c = 0; c < 4; ++c) { float4 v = r4[kk + 16*c]; s = d4(v, v, s); }
    #pragma unroll
    for (int off = 1; off < 16; off <<= 1) s += __shfl_xor(s, off);
    if (kk == 0) {
        float2 g = ((const float2*)gps)[row];
        prep[row] = make_float4(s, g.x, g.y, cosf(g.x * D2R));
    }
}

// K2: register-tiled GEMM 32i x 64j per block (128 thr, thread tile 4x4).
// Emits: d2 matrix, per-(i,jb) pmax^2/nmin^2 partials, neg bitmask.
__global__ __launch_bounds__(128) void gemm_kernel(
    const float* __restrict__ emb, const float4* __restrict__ prep,
    float4* __restrict__ d2, float* __restrict__ pP, float* __restrict__ nP,
    unsigned* __restrict__ negm)
{
    __shared__ float4 iT[2][32][8];      // 8 KB  (k-chunk = 32 floats)
    __shared__ float4 jT[2][64][8];      // 16 KB
    __shared__ float4 sPi[32], sPj[64];
    __shared__ float  pRed[32][16], nRed[32][16];
    __shared__ unsigned nmw[32][2];

    const int tid = threadIdx.x;
    const int ti  = tid >> 4;            // 0..7  -> i rows ti*4..+3
    const int tj  = tid & 15;            // 0..15 -> j rows tj*4..+3
    const int ib  = blockIdx.x & 31, jb = blockIdx.x >> 5;
    const int i0  = ib*32, j0 = jb*64;
    const float4* emb4 = (const float4*)emb;

    if (tid < 32) sPi[tid] = prep[i0 + tid];
    if (tid >= 32 && tid < 96) sPj[tid-32] = prep[j0 + tid - 32];
    if (tid < 64) nmw[tid>>1][tid&1] = 0u;

    // prefetch chunk 0 into registers
    float4 pi[2], pj[4];
    #pragma unroll
    for (int q = 0; q < 2; ++q) {
        int S = tid + 128*q, r = S>>3, s = S&7;
        pi[q] = emb4[(size_t)(i0+r)*64 + s];
    }
    #pragma unroll
    for (int q = 0; q < 4; ++q) {
        int S = tid + 128*q, r = S>>3, s = S&7;
        pj[q] = emb4[(size_t)(j0+r)*64 + s];
    }

    float acc[4][4];
    #pragma unroll
    for (int a = 0; a < 4; ++a)
        #pragma unroll
        for (int b = 0; b < 4; ++b) acc[a][b] = 0.f;

    #pragma unroll
    for (int kt = 0; kt < 8; ++kt) {
        const int buf = kt & 1;
        // store prefetched regs to LDS, rotate-swizzled: slot = (s + (r>>2)) & 7
        #pragma unroll
        for (int q = 0; q < 2; ++q) {
            int S = tid + 128*q, r = S>>3, s = S&7;
            iT[buf][r][(s + (r>>2)) & 7] = pi[q];
        }
        #pragma unroll
        for (int q = 0; q < 4; ++q) {
            int S = tid + 128*q, r = S>>3, s = S&7;
            jT[buf][r][(s + (r>>2)) & 7] = pj[q];
        }
        __syncthreads();                 // single barrier per chunk
        if (kt < 7) {                    // issue next chunk's loads (hide under compute)
            #pragma unroll
            for (int q = 0; q < 2; ++q) {
                int S = tid + 128*q, r = S>>3, s = S&7;
                pi[q] = emb4[(size_t)(i0+r)*64 + (kt+1)*8 + s];
            }
            #pragma unroll
            for (int q = 0; q < 4; ++q) {
                int S = tid + 128*q, r = S>>3, s = S&7;
                pj[q] = emb4[(size_t)(j0+r)*64 + (kt+1)*8 + s];
            }
        }
        #pragma unroll
        for (int kk = 0; kk < 8; ++kk) {
            float4 iOp[4], jOp[4];
            #pragma unroll
            for (int ii = 0; ii < 4; ++ii) iOp[ii] = iT[buf][ti*4+ii][(kk + ti) & 7];
            #pragma unroll
            for (int jj = 0; jj < 4; ++jj) jOp[jj] = jT[buf][tj*4+jj][(kk + tj) & 7];
            #pragma unroll
            for (int ii = 0; ii < 4; ++ii)
                #pragma unroll
                for (int jj = 0; jj < 4; ++jj)
                    acc[ii][jj] = d4(iOp[ii], jOp[jj], acc[ii][jj]);
        }
    }

    // epilogue: d^2, haversine masks, partials, bitmask, d2 store
    float4 PI[4], PJ[4];
    #pragma unroll
    for (int ii = 0; ii < 4; ++ii) PI[ii] = sPi[ti*4+ii];
    #pragma unroll
    for (int jj = 0; jj < 4; ++jj) PJ[jj] = sPj[tj*4+jj];

    #pragma unroll
    for (int ii = 0; ii < 4; ++ii) {
        const int gi = i0 + ti*4 + ii;
        float pmax = -1.f, nmin = BIGV;
        unsigned nib = 0;
        float dd[4];
        #pragma unroll
        for (int jj = 0; jj < 4; ++jj) {
            const int gj = j0 + tj*4 + jj;
            float d2v = PI[ii].x + PJ[jj].x - 2.f*acc[ii][jj];
            d2v = d2v > 0.f ? d2v : 0.f;
            float sla = sinf((PJ[jj].y - PI[ii].y) * HD2R);
            float slo = sinf((PJ[jj].z - PI[ii].z) * HD2R);
            float hav = fmaf(sla, sla, (PI[ii].w * PJ[jj].w) * (slo*slo));
            bool pos = (hav < A_POS) && (gi != gj);
            bool neg = (hav > A_NEG);
            pmax = fmaxf(pmax, pos ? d2v : -1.f);
            nmin = fminf(nmin, neg ? d2v : BIGV);
            nib |= (neg ? 1u : 0u) << jj;
            dd[jj] = d2v;
        }
        d2[(size_t)gi*256 + jb*16 + tj] = make_float4(dd[0], dd[1], dd[2], dd[3]);
        pRed[ti*4+ii][tj] = pmax;
        nRed[ti*4+ii][tj] = nmin;
        atomicOr(&nmw[ti*4+ii][tj>>3], nib << ((tj & 7)*4));
    }
    __syncthreads();
    if (tid < 32) {
        float m = pRed[tid][0], n = nRed[tid][0];
        #pragma unroll
        for (int t = 1; t < 16; ++t) { m = fmaxf(m, pRed[tid][t]); n = fminf(n, nRed[tid][t]); }
        pP[(i0+tid)*16 + jb] = m;
        nP[(i0+tid)*16 + jb] = n;
    }
    if (tid < 64) negm[(size_t)(i0 + (tid>>1))*32 + jb*2 + (tid&1)] = nmw[tid>>1][tid&1];
}

// K3: per-row: reduce partials -> dap^2/nmin^2; windowed scan of d2 row for semi-min.
__global__ __launch_bounds__(256) void rows_kernel(
    const float4* __restrict__ d2, const float* __restrict__ pP,
    const float* __restrict__ nP, const unsigned* __restrict__ negm,
    float* __restrict__ tri, float* __restrict__ val)
{
    const int tid = threadIdx.x, lane = tid & 63, wave = tid >> 6;
    const int i = blockIdx.x*4 + wave;

    float p = pP[i*16 + (lane & 15)];
    float n = nP[i*16 + (lane & 15)];
    #pragma unroll
    for (int off = 1; off < 16; off <<= 1) {
        p = fmaxf(p, __shfl_xor(p, off));
        n = fminf(n, __shfl_xor(n, off));
    }
    bool has_pos = p > -0.5f;
    float lo2 = -1.f, hi2 = -1.f;
    if (has_pos) { float hb = sqrtf(p) + MARGINF; lo2 = p; hi2 = hb*hb; }

    float smin = BIGV;
    const float4* row = d2 + (size_t)i*256;
    #pragma unroll
    for (int pass = 0; pass < 4; ++pass) {
        float4 v = row[pass*64 + lane];
        unsigned w = negm[i*32 + pass*8 + (lane>>3)];
        unsigned nb = (w >> ((lane & 7)*4)) & 15u;
        #pragma unroll
        for (int q = 0; q < 4; ++q) {
            float dv = (q==0) ? v.x : (q==1) ? v.y : (q==2) ? v.z : v.w;
            bool ok = ((nb >> q) & 1u) && (dv > lo2) && (dv < hi2);
            smin = fminf(smin, ok ? dv : BIGV);
        }
    }
    #pragma unroll
    for (int off = 1; off < 64; off <<= 1) smin = fminf(smin, __shfl_xor(smin, off));
    if (lane == 0) {
        bool has_neg  = n < 0.5f*BIGV;
        bool has_semi = smin < 0.5f*BIGV;
        float dan = sqrtf(has_semi ? smin : n);
        float dap = has_pos ? sqrtf(p) : -1.f;
        float t = dap - dan + MARGINF;
        t = t > 0.f ? t : 0.f;
        bool valid = has_pos && has_neg;
        tri[i] = valid ? t : 0.f;
        val[i] = valid ? 1.f : 0.f;
    }
}

__global__ __launch_bounds__(256) void finalize_kernel(
    const float* __restrict__ tri, const float* __restrict__ val, float* __restrict__ out)
{
    const int tid = threadIdx.x;
    float st = 0.f, sv = 0.f;
    #pragma unroll
    for (int g = 0; g < 4; ++g) { st += tri[tid + (g<<8)]; sv += val[tid + (g<<8)]; }
    #pragma unroll
    for (int off = 1; off < 64; off <<= 1) { st += __shfl_xor(st, off); sv += __shfl_xor(sv, off); }
    __shared__ float rt[4], rv[4];
    if ((tid & 63) == 0) { rt[tid>>6] = st; rv[tid>>6] = sv; }
    __syncthreads();
    if (tid == 0) {
        float t = rt[0]+rt[1]+rt[2]+rt[3];
        float v = rv[0]+rv[1]+rv[2]+rv[3];
        out[0] = t / fmaxf(v, 1.f);
    }
}

// =================== FALLBACK PATH (round-6, proven correct) ===================
template<int PHASE>
__global__ __launch_bounds__(256, 2) void pair_kernel(
    const float* __restrict__ emb, const float* __restrict__ gps,
    float* __restrict__ partP, float* __restrict__ partN, float* __restrict__ partS)
{
    __shared__ float4 sbuf[2][2048];
    __shared__ float  sSqA[8];
    __shared__ float  sRed[4][16];
    const int tid = threadIdx.x, lane = tid & 63, wave = tid >> 6;
    const int g = blockIdx.x >> 2, c = blockIdx.x & 3;
    const int i0 = g*8, jbase = c*256, j = jbase + tid;
    const float4* emb4 = (const float4*)emb;
    {
        int a = tid >> 5, seg = tid & 31;
        float4 p0 = emb4[(i0+a)*64 + seg*2];
        float4 p1 = emb4[(i0+a)*64 + seg*2 + 1];
        float s = d4(p1,p1, d4(p0,p0, 0.f));
        #pragma unroll
        for (int off = 1; off < 32; off <<= 1) s += __shfl_xor(s, off);
        if (seg == 0) sSqA[a] = s;
    }
    unsigned posb = 0, negb = 0;
    {
        float2 gj = ((const float2*)gps)[j];
        float cj = cosf(gj.x * D2R);
        #pragma unroll
        for (int a = 0; a < 8; ++a) {
            float latA = gps[(i0+a)*2], lonA = gps[(i0+a)*2+1];
            float cA = cosf(latA * D2R);
            float sla = sinf((gj.x - latA) * HD2R);
            float slo = sinf((gj.y - lonA) * HD2R);
            float hav = fmaf(sla, sla, (cA*cj)*(slo*slo));
            if ((hav < A_POS) && (j != i0 + a)) posb |= (1u << a);
            if (hav > A_NEG)                    negb |= (1u << a);
        }
    }
    float acc[8] = {0,0,0,0,0,0,0,0};
    float sq = 0.f;
    float4 st[8];
    #pragma unroll
    for (int q = 0; q < 8; ++q) {
        int S = tid + 256*q, r = S >> 3, cc = S & 7;
        st[q] = emb4[(size_t)(jbase + r)*64 + cc];
    }
    #pragma unroll
    for (int q = 0; q < 8; ++q) {
        int S = tid + 256*q, r = S >> 3, cc = S & 7;
        sbuf[0][r*8 + (cc ^ (r & 7))] = st[q];
    }
    __syncthreads();
    #pragma unroll
    for (int kt = 0; kt < 8; ++kt) {
        if (kt < 7) {
            #pragma unroll
            for (int q = 0; q < 8; ++q) {
                int S = tid + 256*q, r = S >> 3, cc = S & 7;
                st[q] = emb4[(size_t)(jbase + r)*64 + (kt+1)*8 + cc];
            }
        }
        #pragma unroll
        for (int s = 0; s < 8; ++s) {
            float4 v = sbuf[kt & 1][tid*8 + (s ^ (tid & 7))];
            sq = d4(v, v, sq);
            #pragma unroll
            for (int a = 0; a < 8; ++a) {
                float4 av = emb4[(i0+a)*64 + kt*8 + s];
                acc[a] = d4(v, av, acc[a]);
            }
        }
        if (kt < 7) {
            #pragma unroll
            for (int q = 0; q < 8; ++q) {
                int S = tid + 256*q, r = S >> 3, cc = S & 7;
                sbuf[(kt+1) & 1][r*8 + (cc ^ (r & 7))] = st[q];
            }
            __syncthreads();
        }
    }
    float red[16];
    if (PHASE == 0) {
        #pragma unroll
        for (int a = 0; a < 8; ++a) {
            float d2v = sSqA[a] + sq - 2.f*acc[a];
            d2v = d2v > 0.f ? d2v : 0.f;
            red[a]   = (posb >> a & 1u) ? d2v : -1.f;
            red[8+a] = (negb >> a & 1u) ? d2v : BIGV;
        }
    } else {
        #pragma unroll
        for (int a = 0; a < 8; ++a) {
            float dap2 = fmaxf(fmaxf(partP[0*NB + i0+a], partP[1*NB + i0+a]),
                               fmaxf(partP[2*NB + i0+a], partP[3*NB + i0+a]));
            float lo2, hi2;
            if (dap2 < 0.f) { lo2 = -1.f; hi2 = -1.f; }
            else { float hb = sqrtf(dap2) + MARGINF; lo2 = dap2; hi2 = hb*hb; }
            float d2v = sSqA[a] + sq - 2.f*acc[a];
            d2v = d2v > 0.f ? d2v : 0.f;
            bool semi = (negb >> a & 1u) && (d2v > lo2) && (d2v < hi2);
            red[a]   = -1.f;
            red[8+a] = semi ? d2v : BIGV;
        }
    }
    #pragma unroll
    for (int off = 1; off < 64; off <<= 1) {
        #pragma unroll
        for (int a = 0; a < 8; ++a) {
            red[a]   = fmaxf(red[a],   __shfl_xor(red[a],   off));
            red[8+a] = fminf(red[8+a], __shfl_xor(red[8+a], off));
        }
    }
    __syncthreads();
    if (lane == 0) {
        #pragma unroll
        for (int v = 0; v < 16; ++v) sRed[wave][v] = red[v];
    }
    __syncthreads();
    if (wave == 0) {
        int w = lane >> 4, idx = lane & 15;
        float x = sRed[w][idx];
        float pp = __shfl_xor(x, 16);
        x = (idx < 8) ? fmaxf(x, pp) : fminf(x, pp);
        pp = __shfl_xor(x, 32);
        x = (idx < 8) ? fmaxf(x, pp) : fminf(x, pp);
        if (w == 0) {
            if (PHASE == 0) {
                if (idx < 8) partP[c*NB + i0 + idx] = x;
                else         partN[c*NB + i0 + idx - 8] = x;
            } else {
                if (idx >= 8) partS[c*NB + i0 + idx - 8] = x;
            }
        }
    }
}

__global__ __launch_bounds__(256) void finalize_fb(
    const float* __restrict__ partP, const float* __restrict__ partN,
    const float* __restrict__ partS, float* __restrict__ out)
{
    const int tid = threadIdx.x;
    float st = 0.f, sv = 0.f;
    #pragma unroll
    for (int q = 0; q < 4; ++q) {
        int i = tid + 256*q;
        float dap2 = fmaxf(fmaxf(partP[i], partP[NB+i]), fmaxf(partP[2*NB+i], partP[3*NB+i]));
        float nm2  = fminf(fminf(partN[i], partN[NB+i]), fminf(partN[2*NB+i], partN[3*NB+i]));
        float sm2  = fminf(fminf(partS[i], partS[NB+i]), fminf(partS[2*NB+i], partS[3*NB+i]));
        bool has_pos  = dap2 > -0.5f;
        bool has_neg  = nm2 < 0.5f*BIGV;
        bool has_semi = sm2 < 0.5f*BIGV;
        float dap = has_pos ? sqrtf(dap2) : -1.f;
        float dan = sqrtf(has_semi ? sm2 : nm2);
        float t = dap - dan + MARGINF;
        t = t > 0.f ? t : 0.f;
        bool valid = has_pos && has_neg;
        st += valid ? t : 0.f;
        sv += valid ? 1.f : 0.f;
    }
    #pragma unroll
    for (int off = 1; off < 64; off <<= 1) { st += __shfl_xor(st, off); sv += __shfl_xor(sv, off); }
    __shared__ float rt[4], rv[4];
    if ((tid & 63) == 0) { rt[tid>>6] = st; rv[tid>>6] = sv; }
    __syncthreads();
    if (tid == 0) {
        float t = rt[0]+rt[1]+rt[2]+rt[3];
        float v = rv[0]+rv[1]+rv[2]+rv[3];
        out[0] = t / fmaxf(v, 1.f);
    }
}

extern "C" void kernel_launch(void* const* d_in, const int* in_sizes, int n_in,
                              void* d_out, int out_size, void* d_ws, size_t ws_size,
                              hipStream_t stream) {
    const float* emb = (const float*)d_in[0];   // [1024,256] f32
    const float* gps = (const float*)d_in[1];   // [1024,2]  f32
    float* ws = (float*)d_ws;

    // float offsets in ws
    const size_t OFF_D2   = 0;              // 1024*1024
    const size_t OFF_PREP = 1048576;        // 4096 (1024 float4)
    const size_t OFF_PP   = OFF_PREP + 4096;    // 1024*16
    const size_t OFF_NP   = OFF_PP + 16384;     // 1024*16
    const size_t OFF_NM   = OFF_NP + 16384;     // 1024*32 (uint32)
    const size_t OFF_TRI  = OFF_NM + 32768;     // 1024
    const size_t OFF_VAL  = OFF_TRI + 1024;     // 1024
    const size_t NEED = (OFF_VAL + 1024) * sizeof(float);   // ~4.48 MB

    if (ws_size >= NEED) {
        float4*   prep = (float4*)(ws + OFF_PREP);
        float4*   d2   = (float4*)(ws + OFF_D2);
        float*    pP   = ws + OFF_PP;
        float*    nP   = ws + OFF_NP;
        unsigned* nm   = (unsigned*)(ws + OFF_NM);
        float*    tri  = ws + OFF_TRI;
        float*    val  = ws + OFF_VAL;
        prep_kernel<<<64, 256, 0, stream>>>(emb, gps, prep);
        gemm_kernel<<<512, 128, 0, stream>>>(emb, prep, d2, pP, nP, nm);
        rows_kernel<<<256, 256, 0, stream>>>(d2, pP, nP, nm, tri, val);
        finalize_kernel<<<1, 256, 0, stream>>>(tri, val, (float*)d_out);
    } else {
        float* partP = ws;                 // [4][1024]
        float* partN = partP + 4*NB;
        float* partS = partN + 4*NB;
        pair_kernel<0><<<512, 256, 0, stream>>>(emb, gps, partP, partN, partS);
        pair_kernel<1><<<512, 256, 0, stream>>>(emb, gps, partP, partN, partS);
        finalize_fb<<<1, 256, 0, stream>>>(partP, partN, partS, (float*)d_out);
    }
}

// Round 8
// 29.348 us; speedup vs baseline: 3.9300x; 3.9300x over previous
//
#include <hip/hip_runtime.h>

#define NB 1024
#define ND 256
#define APB 8              // anchors per block
#define JCH 256            // j's per block
#define NTHR 256           // 4 waves
#define MARGINF 0.3f
#define BIGV 1e9f
#define D2R 0.017453292519943295f
#define HD2R 0.008726646259971648f

// haversine 'a' thresholds: sin^2(T/(2*6371000)) (validated rounds 1-7)
#define A_POS 3.8495040e-12f   // 25 m
#define A_NEG 6.1592064e-11f   // 100 m

__device__ __forceinline__ float d4(float4 a, float4 b, float acc) {
    return fmaf(a.x,b.x, fmaf(a.y,b.y, fmaf(a.z,b.z, fmaf(a.w,b.w, acc))));
}

// Splitting butterfly: 8 values spread over each 16-lane group -> lane ends up
// holding the FULL 16-lane sum for anchor a(lane) = 4*(l&1)+2*((l>>1)&1)+((l>>2)&1).
// 8 shuffles instead of 32 (plain per-anchor butterflies).
__device__ __forceinline__ float reduce8(const float v[8], int lane) {
    const bool b0 = lane & 1, b1 = lane & 2, b2 = lane & 4;
    float n1[4];
    #pragma unroll
    for (int i = 0; i < 4; ++i) {
        float sv = b0 ? v[i]   : v[4+i];   // odd sends low, even sends high
        float kp = b0 ? v[4+i] : v[i];     // odd keeps high, even keeps low
        n1[i] = kp + __shfl_xor(sv, 1);
    }
    float n2[2];
    #pragma unroll
    for (int i = 0; i < 2; ++i) {
        float sv = b1 ? n1[i]   : n1[2+i];
        float kp = b1 ? n1[2+i] : n1[i];
        n2[i] = kp + __shfl_xor(sv, 2);
    }
    float sv = b2 ? n2[0] : n2[1];
    float kp = b2 ? n2[1] : n2[0];
    float n3 = kp + __shfl_xor(sv, 4);
    return n3 + __shfl_xor(n3, 8);         // merge the duplicate half-group
}

// K2: no-LDS gram kernel. Block = 8 anchors x 256 j's. Lane layout: jj=lane>>4
// (4 rows/wave), kk=lane&15 (16-way k-split, slice = float4 idx {kk,kk+16,kk+32,kk+48}).
// Anchors live in 128 VGPRs, reused for all 256 j's. Emits:
//   sEnc[i][j] = neg ? d^2 : BIGV    (neg mask folded into the value)
//   pP[i][chunk] = max over pos of d^2 (or -1)
__global__ __launch_bounds__(NTHR, 2) void gram_kernel(
    const float* __restrict__ emb, const float* __restrict__ gps,
    float* __restrict__ sEnc, float* __restrict__ pP)
{
    __shared__ float sPm[4][APB];

    const int tid  = threadIdx.x;
    const int lane = tid & 63;
    const int w    = tid >> 6;
    const int jj   = lane >> 4;
    const int kk   = lane & 15;
    const int ig   = blockIdx.x >> 2;
    const int c    = blockIdx.x & 3;
    const int i0   = ig * APB;
    const int jbase = c * JCH;
    const int a    = 4*(lane & 1) + 2*((lane >> 1) & 1) + ((lane >> 2) & 1);
    const float4* __restrict__ emb4 = (const float4*)emb;

    // anchors into registers: 8 anchors x 16-float slice = 32 float4 = 128 VGPR
    float4 cA[APB][4];
    #pragma unroll
    for (int ai = 0; ai < APB; ++ai)
        #pragma unroll
        for (int q = 0; q < 4; ++q)
            cA[ai][q] = emb4[(size_t)(i0+ai)*64 + kk + 16*q];

    // anchor squared norms -> this lane's anchor's SA
    float sp[APB];
    #pragma unroll
    for (int ai = 0; ai < APB; ++ai) {
        float s = 0.f;
        #pragma unroll
        for (int q = 0; q < 4; ++q) s = d4(cA[ai][q], cA[ai][q], s);
        sp[ai] = s;
    }
    const float SA = reduce8(sp, lane);

    // this lane's anchor gps scalars (one-time)
    const float latA = gps[2*(i0+a)];
    const float lonA = gps[2*(i0+a)+1];
    const float cosA = cosf(latA * D2R);

    float pmax = -1.f;

    // software-pipelined j loop: 16 t-iters x 4 rows/wave
    int j = jbase + w*4 + jj;
    float4 v0 = emb4[(size_t)j*64 + kk],      v1 = emb4[(size_t)j*64 + kk+16],
           v2 = emb4[(size_t)j*64 + kk+32],   v3 = emb4[(size_t)j*64 + kk+48];

    #pragma unroll 2
    for (int t = 0; t < 16; ++t) {
        float4 w0, w1, w2, w3;
        if (t < 15) {
            const int jn = jbase + (t+1)*16 + w*4 + jj;
            w0 = emb4[(size_t)jn*64 + kk];    w1 = emb4[(size_t)jn*64 + kk+16];
            w2 = emb4[(size_t)jn*64 + kk+32]; w3 = emb4[(size_t)jn*64 + kk+48];
        }
        // dots: 8 anchors + self
        float sq = d4(v3,v3, d4(v2,v2, d4(v1,v1, d4(v0,v0, 0.f))));
        float ac[APB];
        #pragma unroll
        for (int ai = 0; ai < APB; ++ai)
            ac[ai] = d4(v3, cA[ai][3], d4(v2, cA[ai][2], d4(v1, cA[ai][1], d4(v0, cA[ai][0], 0.f))));
        // row norm: plain butterfly over the 16-lane group (all lanes get it)
        #pragma unroll
        for (int off = 1; off < 16; off <<= 1) sq += __shfl_xor(sq, off);
        // 8 dots -> this lane's anchor's dot (full 16-lane sum)
        const float dot = reduce8(ac, lane);

        float d2v = SA + sq - 2.f*dot;
        d2v = d2v > 0.f ? d2v : 0.f;

        const float2 gj = ((const float2*)gps)[j];
        const float cj  = cosf(gj.x * D2R);
        const float sla = sinf((gj.x - latA) * HD2R);
        const float slo = sinf((gj.y - lonA) * HD2R);
        const float hav = fmaf(sla, sla, (cosA*cj) * (slo*slo));
        const bool pos = (hav < A_POS) && (j != i0 + a);
        const bool neg = (hav > A_NEG);

        pmax = fmaxf(pmax, pos ? d2v : -1.f);
        if (!(lane & 8))                       // one writer per (a, j)
            sEnc[(size_t)(i0+a)*NB + j] = neg ? d2v : BIGV;

        j = jbase + (t+1)*16 + w*4 + jj;
        v0 = w0; v1 = w1; v2 = w2; v3 = w3;
    }

    // reduce pmax over lanes sharing the same anchor (bits 3,4,5)
    #pragma unroll
    for (int off = 8; off < 64; off <<= 1) pmax = fmaxf(pmax, __shfl_xor(pmax, off));
    if (lane < 8) sPm[w][a] = pmax;            // a covers 0..7 over lanes 0..7
    __syncthreads();
    if (tid < 32) {
        float x = sPm[tid >> 3][tid & 7];
        x = fmaxf(x, __shfl_xor(x, 8));
        x = fmaxf(x, __shfl_xor(x, 16));
        if (tid < 8) pP[(i0 + tid)*4 + c] = x;
    }
}

// K3: per-row finalize. Wave owns row i: dap^2 from pP, then one pass over the
// encoded row for nmin (all negs) and smin (semi-hard window), then tri/val.
__global__ __launch_bounds__(256) void rows_kernel(
    const float* __restrict__ sEnc, const float* __restrict__ pP,
    float* __restrict__ tri, float* __restrict__ val)
{
    const int tid = threadIdx.x, lane = tid & 63, w = tid >> 6;
    const int i = blockIdx.x*4 + w;

    const float dap2 = fmaxf(fmaxf(pP[i*4+0], pP[i*4+1]), fmaxf(pP[i*4+2], pP[i*4+3]));
    const bool has_pos = dap2 > -0.5f;
    float lo2 = -1.f, hi2 = -1.f;
    if (has_pos) { const float hb = sqrtf(dap2) + MARGINF; lo2 = dap2; hi2 = hb*hb; }

    float nmin = BIGV, smin = BIGV;
    const float4* __restrict__ row = (const float4*)sEnc + (size_t)i*256;
    #pragma unroll
    for (int p = 0; p < 4; ++p) {
        const float4 x = row[p*64 + lane];
        #pragma unroll
        for (int q = 0; q < 4; ++q) {
            const float xc = (q==0) ? x.x : (q==1) ? x.y : (q==2) ? x.z : x.w;
            nmin = fminf(nmin, xc);
            smin = fminf(smin, (xc > lo2 && xc < hi2) ? xc : BIGV);
        }
    }
    #pragma unroll
    for (int off = 1; off < 64; off <<= 1) {
        nmin = fminf(nmin, __shfl_xor(nmin, off));
        smin = fminf(smin, __shfl_xor(smin, off));
    }
    if (lane == 0) {
        const bool has_neg  = nmin < 0.5f*BIGV;
        const bool has_semi = smin < 0.5f*BIGV;
        const float dan2 = has_semi ? smin : nmin;
        const float dap  = has_pos ? sqrtf(dap2) : 0.f;
        float t = dap - sqrtf(dan2) + MARGINF;
        t = t > 0.f ? t : 0.f;
        const bool valid = has_pos && has_neg;
        tri[i] = valid ? t : 0.f;
        val[i] = valid ? 1.f : 0.f;
    }
}

__global__ __launch_bounds__(256) void finalize_kernel(
    const float* __restrict__ tri, const float* __restrict__ val, float* __restrict__ out)
{
    const int tid = threadIdx.x;
    float st = 0.f, sv = 0.f;
    #pragma unroll
    for (int g = 0; g < 4; ++g) { st += tri[tid + (g<<8)]; sv += val[tid + (g<<8)]; }
    #pragma unroll
    for (int off = 1; off < 64; off <<= 1) { st += __shfl_xor(st, off); sv += __shfl_xor(sv, off); }
    __shared__ float rt[4], rv[4];
    if ((tid & 63) == 0) { rt[tid>>6] = st; rv[tid>>6] = sv; }
    __syncthreads();
    if (tid == 0) {
        float t = rt[0]+rt[1]+rt[2]+rt[3];
        float v = rv[0]+rv[1]+rv[2]+rv[3];
        out[0] = t / fmaxf(v, 1.f);
    }
}

extern "C" void kernel_launch(void* const* d_in, const int* in_sizes, int n_in,
                              void* d_out, int out_size, void* d_ws, size_t ws_size,
                              hipStream_t stream) {
    const float* emb = (const float*)d_in[0];   // [1024,256] f32
    const float* gps = (const float*)d_in[1];   // [1024,2]  f32
    float* ws = (float*)d_ws;

    float* sEnc = ws;                    // [1024*1024]  4 MB
    float* pP   = ws + 1048576;          // [1024*4]
    float* tri  = pP + 4096;             // [1024]
    float* val  = tri + 1024;            // [1024]

    gram_kernel<<<512, NTHR, 0, stream>>>(emb, gps, sEnc, pP);
    rows_kernel<<<256, 256, 0, stream>>>(sEnc, pP, tri, val);
    finalize_kernel<<<1, 256, 0, stream>>>(tri, val, (float*)d_out);
}